// Round 5
// baseline (2600.507 us; speedup 1.0000x reference)
//
#include <hip/hip_runtime.h>

// ---------------------------------------------------------------------------
// ParamMemAdam: hs features collapse to a 64-entry token table. 256
// independent sequential Adam scans (3069 steps) -> one block per batch
// element. R5: wave specialization (512 thr: waves 0-3 = w2-layer B/C +
// w2-Adam, waves 4-7 = w1-layer D/A + w1-Adam) so w2-Adam's issue overlaps
// the w1 critical path and occupancy doubles (2 waves/SIMD). C-reduce DS
// chain (swz16+bpermute, ~200cy serial) replaced by post-xor8 partial store
// + exact-tree re-sum in D. All values bit-identical to R1/R3/R4 trajectory.
// ---------------------------------------------------------------------------

template <int CTRL>
__device__ __forceinline__ float dpp_add(float x) {
  union { float f; int i; } u, r;
  u.f = x;
  r.i = __builtin_amdgcn_update_dpp(0, u.i, CTRL, 0xF, 0xF, true);
  return x + r.f;
}

// Bit-identical to R1's update.
__device__ __forceinline__ void adam_upd(float& p, float& m1, float& m2,
                                         float g, float c2inv, float nls)
{
  m1 = fmaf(0.9f,  m1, 0.1f   * g);
  m2 = fmaf(0.999f, m2, 0.001f * (g * g));
  float den = __builtin_amdgcn_sqrtf(m2 * c2inv) + 1e-8f;
  p = fmaf(nls * m1, __builtin_amdgcn_rcpf(den), p);
}

// ---- prep: hs_table[v][j] = LN(e_v + FF(e_v)) for the 64 possible tokens ----
__global__ void prep_kernel(const float* __restrict__ emb,
                            const float* __restrict__ ffw1, const float* __restrict__ ffb1,
                            const float* __restrict__ ffw2, const float* __restrict__ ffb2,
                            const float* __restrict__ lng,  const float* __restrict__ lnb,
                            float* __restrict__ hs_out)
{
  const int v = blockIdx.x;   // token id
  const int t = threadIdx.x;  // 128 threads
  __shared__ float e[64];
  __shared__ float r[128];
  if (t < 64) e[t] = emb[v * 64 + t];
  __syncthreads();
  {
    float s = ffb1[t];
    const float* wrow = ffw1 + t * 64;
#pragma unroll 8
    for (int m = 0; m < 64; ++m) s = fmaf(wrow[m], e[m], s);
    r[t] = fmaxf(s, 0.f);
  }
  __syncthreads();
  if (t < 64) {
    float s = ffb2[t];
    const float* wrow = ffw2 + t * 128;
#pragma unroll 8
    for (int o = 0; o < 128; ++o) s = fmaf(wrow[o], r[o], s);
    float x = e[t] + s;
    float mu = x;
    for (int m = 1; m < 64; m <<= 1) mu += __shfl_xor(mu, m, 64);
    mu *= (1.f / 64.f);
    float dv = x - mu;
    float var = dv * dv;
    for (int m = 1; m < 64; m <<= 1) var += __shfl_xor(var, m, 64);
    var *= (1.f / 64.f);
    float hs = dv / sqrtf(var + 1e-5f);
    hs_out[v * 64 + t] = hs * lng[t] + lnb[t];
  }
}

// ---- per-step Adam scale table: EXACT op sequence of the R1 in-loop code ----
__global__ __launch_bounds__(64)
void table_kernel(float* __restrict__ tab)   // tab[2n] = nls, tab[2n+1] = c2inv
{
  if (threadIdx.x != 0) return;
  double pb1 = 1.0, pb2 = 1.0;
  for (int n = 0; n < 3069; ++n) {
    pb1 *= 0.9; pb2 *= 0.999;
    float c1inv = __builtin_amdgcn_rcpf((float)(1.0 - pb1));
    float c2inv = __builtin_amdgcn_rcpf((float)(1.0 - pb2));
    tab[2 * n]     = -0.05f * c1inv;
    tab[2 * n + 1] = c2inv;
  }
}

// ---- main scan: one block per batch element, 8 waves ----------------------
// Waves 0-3 (t<256, "w2-waves"): lane mapping == old t. Own w2 rows
// p0,p0+1 x cols c0..c0+3 + b2 pair. Do B (pred+dd), C (dp, xor8, store),
// w2/b2 Adam, v prefetch, epilogue ctx.
// Waves 4-7 (tl=t-256, "w1-waves"): lane mapping == old t. Own w1 row i1
// cols j0..j0+7 + b1. Do k prefetch, D (dh exact tree + w1/b1 Adam),
// A (matvec, relu, h_s write).
__global__ __launch_bounds__(512)
void scan_kernel(const int* __restrict__ seq, const float* __restrict__ hs_tab,
                 const float* __restrict__ tab_g,
                 const float* __restrict__ fc1w, const float* __restrict__ fc1b,
                 const float* __restrict__ fc2w, const float* __restrict__ fc2b,
                 const float* __restrict__ outw, const float* __restrict__ outb,
                 float* __restrict__ out)
{
  const int b      = blockIdx.x;
  const int t      = threadIdx.x;      // 0..511
  const bool isw2  = (t < 256);
  const int tl     = t & 255;          // role-local id, same mapping as old t
  const int lane   = tl & 63;
  const int wv     = tl >> 6;          // 0..3 within role
  const int i1     = tl >> 3;          // 0..31
  const int j0     = (tl & 7) << 3;    // w1 col base (w1-waves)
  const int p0     = i1 << 1;          // w2 row base / v index
  const int c0     = (tl & 7) << 2;    // h col base (w2-waves)
  const int sub    = tl & 7;

  __shared__ __align__(16) float hs[4096];     // token table 64x64
  __shared__ __align__(16) int   sq[2048];     // this batch's token ids
  __shared__ __align__(16) float tabs[6144];   // (nls, c2inv) per step
  __shared__ __align__(16) float h_s[32];      // hidden vector
  __shared__ __align__(16) float dhp[32][20];  // dh partials [h-col][wv*4+q]
  __shared__ __align__(16) float ctx[64];      // final context

  for (int i = t; i < 1024; i += 512)
    ((float4*)hs)[i] = ((const float4*)hs_tab)[i];
  {
    const int4* sg = (const int4*)(seq + (long long)b * 2048);
    ((int4*)sq)[t] = sg[t];
  }
  for (int i = t; i < 1536; i += 512)
    ((float4*)tabs)[i] = ((const float4*)tab_g)[i];

  // ---- per-role parameter state in registers
  float w1r[8], m1a[8], m2a[8];                 // w1-waves
  float b1v = 0.f, m1c = 0.f, m2c = 0.f;
  float w2r[8], m1b[8], m2b[8];                 // w2-waves
  float b2v0 = 0.f, m1d0 = 0.f, m2d0 = 0.f;
  float b2v1 = 0.f, m1d1 = 0.f, m2d1 = 0.f;
  if (isw2) {
#pragma unroll
    for (int z = 0; z < 8; ++z) {
      w2r[z] = fc2w[(p0 + (z >> 2)) * 32 + c0 + (z & 3)];
      m1b[z] = 0.f; m2b[z] = 0.f;
    }
    b2v0 = fc2b[p0];
    b2v1 = fc2b[p0 + 1];
  } else {
#pragma unroll
    for (int jj = 0; jj < 8; ++jj) {
      w1r[jj] = fc1w[i1 * 64 + j0 + jj];
      m1a[jj] = 0.f; m2a[jj] = 0.f;
    }
    b1v = fc1b[i1];
  }

  __syncthreads();

  int jm = 1;           // pair index for step+1
  float kk[8], hv = 0.f, v0 = 0.f, v1 = 0.f;

  // ---- prologue: pair 0. w1-waves: A(0) -> h_s. w2-waves: v(0).
  if (!isw2) {
    const int ka = sq[0];
    const float4 k0 = *(const float4*)(hs + ka * 64 + j0);
    const float4 k1 = *(const float4*)(hs + ka * 64 + j0 + 4);
    kk[0]=k0.x; kk[1]=k0.y; kk[2]=k0.z; kk[3]=k0.w;
    kk[4]=k1.x; kk[5]=k1.y; kk[6]=k1.z; kk[7]=k1.w;
    float pa = 0.f;
#pragma unroll
    for (int jj = 0; jj < 8; ++jj) pa = fmaf(w1r[jj], kk[jj], pa);
    pa = dpp_add<0xB1>(pa);   // xor1
    pa = dpp_add<0x4E>(pa);   // xor2
    pa = dpp_add<0x141>(pa);  // xor4-equiv (row_half_mirror)
    hv = fmaxf(pa + b1v, 0.f);
    if (sub == 1) h_s[i1] = hv;
  } else {
    const int vb = sq[1];
    v0 = hs[vb * 64 + p0];
    v1 = hs[vb * 64 + p0 + 1];
  }
  __syncthreads();   // Y_{-1}

  for (int step = 0; step < 3069; ++step) {
    const float nls   = tabs[2 * step];
    const float c2inv = tabs[2 * step + 1];

    float kn[8];
    float hh[4];
    float dd0 = 0.f, dd1 = 0.f;

    // ======== interval 1 (Y_{s-1} -> X_s) ========
    if (isw2) {
      // B: pred = w2 h + b2 ; d = (2/64)(pred - v)
      const float4 h4 = *(const float4*)(h_s + c0);
      hh[0]=h4.x; hh[1]=h4.y; hh[2]=h4.z; hh[3]=h4.w;
      float q0 = 0.f, q1 = 0.f;
#pragma unroll
      for (int ii = 0; ii < 4; ++ii) {
        q0 = fmaf(w2r[ii],     hh[ii], q0);
        q1 = fmaf(w2r[4 + ii], hh[ii], q1);
      }
      q0 = dpp_add<0xB1>(q0);   q1 = dpp_add<0xB1>(q1);
      q0 = dpp_add<0x4E>(q0);   q1 = dpp_add<0x4E>(q1);
      q0 = dpp_add<0x141>(q0);  q1 = dpp_add<0x141>(q1);
      dd0 = 0.03125f * (q0 + b2v0 - v0);
      dd1 = 0.03125f * (q1 + b2v1 - v1);

      // C: dp partials with OLD w2; xor8; store 4 partials/col (exact tree)
      float dp[4];
#pragma unroll
      for (int ii = 0; ii < 4; ++ii)
        dp[ii] = fmaf(w2r[4 + ii], dd1, w2r[ii] * dd0);
#pragma unroll
      for (int ii = 0; ii < 4; ++ii) dp[ii] = dpp_add<0x128>(dp[ii]);  // xor8
      if (!(lane & 8)) {
        const int slot = wv * 4 + (lane >> 4);
        const int colb = (lane & 7) << 2;
        dhp[colb + 0][slot] = dp[0];
        dhp[colb + 1][slot] = dp[1];
        dhp[colb + 2][slot] = dp[2];
        dhp[colb + 3][slot] = dp[3];
      }
    } else {
      // prefetch k(step+1) (query token on last step)
      const int ka = (step < 3068) ? sq[2 * jm] : sq[2047];
      const float4 k0 = *(const float4*)(hs + ka * 64 + j0);
      const float4 k1 = *(const float4*)(hs + ka * 64 + j0 + 4);
      kn[0]=k0.x; kn[1]=k0.y; kn[2]=k0.z; kn[3]=k0.w;
      kn[4]=k1.x; kn[5]=k1.y; kn[6]=k1.z; kn[7]=k1.w;
    }
    __syncthreads();   // X_s

    // ======== interval 2 (X_s -> Y_s) ========
    if (isw2) {
      // w2/b2 Adam (off the recurrence critical path)
#pragma unroll
      for (int ii = 0; ii < 4; ++ii) {
        adam_upd(w2r[ii],     m1b[ii],     m2b[ii],     dd0 * hh[ii], c2inv, nls);
        adam_upd(w2r[4 + ii], m1b[4 + ii], m2b[4 + ii], dd1 * hh[ii], c2inv, nls);
      }
      adam_upd(b2v0, m1d0, m2d0, dd0, c2inv, nls);
      adam_upd(b2v1, m1d1, m2d1, dd1, c2inv, nls);
      // prefetch v(step+1)
      const int vb = (step < 3068) ? sq[2 * jm + 1] : 0;
      jm = (jm == 1022) ? 0 : jm + 1;
      v0 = hs[vb * 64 + p0];
      v1 = hs[vb * 64 + p0 + 1];
    } else {
      // D: dh from 16 partials, exact xor-tree order
      const float4 pA = *(const float4*)&dhp[i1][0];
      const float4 pB = *(const float4*)&dhp[i1][4];
      const float4 pC = *(const float4*)&dhp[i1][8];
      const float4 pD = *(const float4*)&dhp[i1][12];
      const float W0 = (pA.x + pA.y) + (pA.z + pA.w);
      const float W1 = (pB.x + pB.y) + (pB.z + pB.w);
      const float W2 = (pC.x + pC.y) + (pC.z + pC.w);
      const float W3 = (pD.x + pD.y) + (pD.z + pD.w);
      const float dhsum = (W0 + W1) + (W2 + W3);
      const float dh = (hv > 0.f) ? dhsum : 0.f;
#pragma unroll
      for (int jj = 0; jj < 8; ++jj)
        adam_upd(w1r[jj], m1a[jj], m2a[jj], dh * kk[jj], c2inv, nls);
      adam_upd(b1v, m1c, m2c, dh, c2inv, nls);
      jm = (jm == 1022) ? 0 : jm + 1;
      // A: h(step+1) with updated w1 and prefetched k
#pragma unroll
      for (int jj = 0; jj < 8; ++jj) kk[jj] = kn[jj];
      float pa = 0.f;
#pragma unroll
      for (int jj = 0; jj < 8; ++jj) pa = fmaf(w1r[jj], kk[jj], pa);
      pa = dpp_add<0xB1>(pa);
      pa = dpp_add<0x4E>(pa);
      pa = dpp_add<0x141>(pa);
      hv = fmaxf(pa + b1v, 0.f);
      if (sub == 1) h_s[i1] = hv;
    }
    __syncthreads();   // Y_s
  }

  // ---- epilogue: ctx = w2 h_q + b2 (no relu on output layer)
  if (isw2) {
    const float4 h4 = *(const float4*)(h_s + c0);
    float q0 = 0.f, q1 = 0.f;
    q0 = fmaf(w2r[0], h4.x, q0); q1 = fmaf(w2r[4], h4.x, q1);
    q0 = fmaf(w2r[1], h4.y, q0); q1 = fmaf(w2r[5], h4.y, q1);
    q0 = fmaf(w2r[2], h4.z, q0); q1 = fmaf(w2r[6], h4.z, q1);
    q0 = fmaf(w2r[3], h4.w, q0); q1 = fmaf(w2r[7], h4.w, q1);
    q0 = dpp_add<0xB1>(q0);   q1 = dpp_add<0xB1>(q1);
    q0 = dpp_add<0x4E>(q0);   q1 = dpp_add<0x4E>(q1);
    q0 = dpp_add<0x141>(q0);  q1 = dpp_add<0x141>(q1);
    if (sub == 2) { ctx[p0] = q0 + b2v0; ctx[p0 + 1] = q1 + b2v1; }
  }
  __syncthreads();

  // ---- output projection: out[b][u] = out_b[u] + sum_p out_w[u][p]*ctx[p]
  if (t < 64) {
    float acc = outb[t];
    const float* wrow = outw + t * 64;
#pragma unroll 8
    for (int p = 0; p < 64; ++p) acc = fmaf(wrow[p], ctx[p], acc);
    out[(long long)b * 64 + t] = acc;
  }
}

extern "C" void kernel_launch(void* const* d_in, const int* in_sizes, int n_in,
                              void* d_out, int out_size, void* d_ws, size_t ws_size,
                              hipStream_t stream) {
  const int*   seq  = (const int*)  d_in[0];
  const float* emb  = (const float*)d_in[1];
  const float* ffw1 = (const float*)d_in[2];
  const float* ffb1 = (const float*)d_in[3];
  const float* ffw2 = (const float*)d_in[4];
  const float* ffb2 = (const float*)d_in[5];
  const float* lng  = (const float*)d_in[6];
  const float* lnb  = (const float*)d_in[7];
  const float* fc1w = (const float*)d_in[8];
  const float* fc1b = (const float*)d_in[9];
  const float* fc2w = (const float*)d_in[10];
  const float* fc2b = (const float*)d_in[11];
  const float* outw = (const float*)d_in[12];
  const float* outb = (const float*)d_in[13];
  float* out    = (float*)d_out;
  float* hs_tab = (float*)d_ws;            // 64*64 floats = 16 KB
  float* tab    = (float*)d_ws + 4096;     // 3069*2 floats (padded to 6144)

  prep_kernel<<<64, 128, 0, stream>>>(emb, ffw1, ffb1, ffw2, ffb2, lng, lnb, hs_tab);
  table_kernel<<<1, 64, 0, stream>>>(tab);
  scan_kernel<<<256, 512, 0, stream>>>(seq, hs_tab, tab, fc1w, fc1b, fc2w, fc2b,
                                       outw, outb, out);
}